// Round 5
// baseline (557.347 us; speedup 1.0000x reference)
//
#include <hip/hip_runtime.h>
#include <hip/hip_fp16.h>

// ---------------------------------------------------------------------------
// DummyFairGCN R5: MFMA fp16 everywhere (incl. lin2 via padded Wt),
// degree-sorted gather order + 8-edge unroll, countdown CSR fill.
// ---------------------------------------------------------------------------

typedef _Float16 f16x8 __attribute__((ext_vector_type(8)));
typedef float f32x4 __attribute__((ext_vector_type(4)));

static inline int cdiv(int a, int b) { return (a + b - 1) / b; }

__global__ __launch_bounds__(256) void k_zero_int(int* p, int n) {
    int i = blockIdx.x * 256 + threadIdx.x;
    if (i < n) p[i] = 0;
}

__global__ __launch_bounds__(256) void k_deg(const int* __restrict__ ei, int E, int* deg) {
    int i = blockIdx.x * 256 + threadIdx.x;
    if (i < E) atomicAdd(&deg[ei[E + i]], 1);
}

__global__ __launch_bounds__(256) void k_dinv(const int* __restrict__ deg, float* dinv, int n) {
    int i = blockIdx.x * 256 + threadIdx.x;
    if (i < n) dinv[i] = rsqrtf((float)(deg[i] + 1));  // +1 self-loop
}

// ---- exclusive scan of deg[N] -> rowptr[N+1] ----
__global__ __launch_bounds__(256) void k_scan1(const int* __restrict__ deg, int* part, int n) {
    __shared__ int s[256];
    int i = blockIdx.x * 256 + threadIdx.x;
    s[threadIdx.x] = (i < n) ? deg[i] : 0;
    __syncthreads();
#pragma unroll
    for (int off = 128; off > 0; off >>= 1) {
        if (threadIdx.x < off) s[threadIdx.x] += s[threadIdx.x + off];
        __syncthreads();
    }
    if (threadIdx.x == 0) part[blockIdx.x] = s[0];
}

__global__ void k_scan2(int* part, int nb) {  // single block, 1024 threads, in-place excl scan
    __shared__ int s[1024];
    int v = (threadIdx.x < nb) ? part[threadIdx.x] : 0;
    s[threadIdx.x] = v;
    __syncthreads();
    for (int off = 1; off < 1024; off <<= 1) {
        int t = (threadIdx.x >= (unsigned)off) ? s[threadIdx.x - off] : 0;
        __syncthreads();
        s[threadIdx.x] += t;
        __syncthreads();
    }
    if (threadIdx.x < nb) part[threadIdx.x] = s[threadIdx.x] - v;
}

__global__ __launch_bounds__(256) void k_scan3(const int* __restrict__ deg,
                                               const int* __restrict__ part,
                                               int* rowptr, int n) {
    __shared__ int s[256];
    int i = blockIdx.x * 256 + threadIdx.x;
    int v = (i < n) ? deg[i] : 0;
    s[threadIdx.x] = v;
    __syncthreads();
    for (int off = 1; off < 256; off <<= 1) {
        int t = (threadIdx.x >= (unsigned)off) ? s[threadIdx.x - off] : 0;
        __syncthreads();
        s[threadIdx.x] += t;
        __syncthreads();
    }
    int excl = part[blockIdx.x] + s[threadIdx.x] - v;
    if (i < n) rowptr[i] = excl;
    if (i == n - 1) rowptr[n] = excl + v;
}

// countdown fill: destroys deg (ends all-zero)
__global__ __launch_bounds__(256) void k_fill_csr(const int* __restrict__ ei, int E,
                                                  const int* __restrict__ rowptr,
                                                  int* deg, int* csr) {
    int e = blockIdx.x * 256 + threadIdx.x;
    if (e >= E) return;
    int src = ei[e];
    int dst = ei[E + e];
    int p = rowptr[dst] + atomicSub(&deg[dst], 1) - 1;
    __builtin_nontemporal_store(src, &csr[p]);
}

// degree histogram (from rowptr diffs), 1024 bins
__global__ __launch_bounds__(256) void k_hist(const int* __restrict__ rowptr, int* hist, int n) {
    int i = blockIdx.x * 256 + threadIdx.x;
    if (i >= n) return;
    int d = rowptr[i + 1] - rowptr[i];
    if (d > 1023) d = 1023;
    atomicAdd(&hist[d], 1);
}

__global__ __launch_bounds__(256) void k_perm(const int* __restrict__ rowptr,
                                              const int* __restrict__ histoff, int* hcur,
                                              int* perm, int n) {
    int i = blockIdx.x * 256 + threadIdx.x;
    if (i >= n) return;
    int d = rowptr[i + 1] - rowptr[i];
    if (d > 1023) d = 1023;
    int pos = histoff[d] + atomicAdd(&hcur[d], 1);
    perm[pos] = i;
}

__global__ __launch_bounds__(256) void k_f2h(const float* __restrict__ x, __half* __restrict__ y,
                                             int n4) {
    int i = blockIdx.x * 256 + threadIdx.x;
    if (i >= n4) return;
    float4 v = ((const float4*)x)[i];
    __half h[4] = {__float2half_rn(v.x), __float2half_rn(v.y), __float2half_rn(v.z),
                   __float2half_rn(v.w)};
    ((uint2*)y)[i] = *(uint2*)h;
}

// W[K x FO] fp32 -> Wt[FOP x K] fp16, zero-padded to FOP cols
__global__ __launch_bounds__(256) void k_wt(const float* __restrict__ W, __half* __restrict__ Wt,
                                            int K, int FO, int FOP) {
    int i = blockIdx.x * 256 + threadIdx.x;
    if (i >= FOP * K) return;
    int c = i / K;
    int k = i - c * K;
    Wt[i] = (c < FO) ? __float2half_rn(W[(size_t)k * FO + c]) : __half(0.f);
}

__device__ inline void unpack8(uint4 v, float* f) {
    __half2* h = (__half2*)&v;
#pragma unroll
    for (int i = 0; i < 4; ++i) {
        float2 t = __half22float2(h[i]);
        f[2 * i] = t.x;
        f[2 * i + 1] = t.y;
    }
}

// CSR gather over 128-wide fp16 rows -> fp16 out (fp32 accum).
// Degree-sorted node order via perm; 16 lanes/node, 16B/lane, 8-edge unroll.
__global__ __launch_bounds__(256) void k_gather128(const int* __restrict__ rowptr,
                                                   const int* __restrict__ csr,
                                                   const int* __restrict__ perm,
                                                   const float* __restrict__ dinv,
                                                   const __half* __restrict__ xh,
                                                   __half* __restrict__ G, int N) {
    int t = blockIdx.x * 256 + threadIdx.x;
    int slot = t >> 4;
    if (slot >= N) return;
    int node = perm[slot];
    int lane = t & 15;
    const uint4* xb = (const uint4*)xh;  // 16 uint4 per row
    float di = dinv[node];
    float acc[8];
    {
        uint4 v = xb[(size_t)node * 16 + lane];
        float f[8];
        unpack8(v, f);
        float s = di * di;
#pragma unroll
        for (int j = 0; j < 8; ++j) acc[j] = s * f[j];
    }
    int p0 = rowptr[node], p1 = rowptr[node + 1];
    int p = p0;
    for (; p + 8 <= p1; p += 8) {
        int s_[8];
        float wg[8];
        uint4 v[8];
#pragma unroll
        for (int j = 0; j < 8; ++j) s_[j] = csr[p + j];
#pragma unroll
        for (int j = 0; j < 8; ++j) wg[j] = di * dinv[s_[j]];
#pragma unroll
        for (int j = 0; j < 8; ++j) v[j] = xb[(size_t)s_[j] * 16 + lane];
#pragma unroll
        for (int j = 0; j < 8; ++j) {
            float f[8];
            unpack8(v[j], f);
#pragma unroll
            for (int k = 0; k < 8; ++k) acc[k] += wg[j] * f[k];
        }
    }
    for (; p + 4 <= p1; p += 4) {
        int s_[4];
        float wg[4];
        uint4 v[4];
#pragma unroll
        for (int j = 0; j < 4; ++j) s_[j] = csr[p + j];
#pragma unroll
        for (int j = 0; j < 4; ++j) wg[j] = di * dinv[s_[j]];
#pragma unroll
        for (int j = 0; j < 4; ++j) v[j] = xb[(size_t)s_[j] * 16 + lane];
#pragma unroll
        for (int j = 0; j < 4; ++j) {
            float f[8];
            unpack8(v[j], f);
#pragma unroll
            for (int k = 0; k < 8; ++k) acc[k] += wg[j] * f[k];
        }
    }
    for (; p < p1; ++p) {
        int src = csr[p];
        float w = di * dinv[src];
        uint4 v = xb[(size_t)src * 16 + lane];
        float f[8];
        unpack8(v, f);
#pragma unroll
        for (int j = 0; j < 8; ++j) acc[j] += w * f[j];
    }
    __half hh[8];
#pragma unroll
    for (int j = 0; j < 8; ++j) hh[j] = __float2half_rn(acc[j]);
    *(uint4*)&G[(size_t)node * 128 + lane * 8] = *(uint4*)hh;
}

// ---------------------------------------------------------------------------
// MFMA fp16 GEMM, fused epilogue (BN+ReLU / bias+ReLU / bias).
// Block = 4 waves; tile 128 rows x 64 cols; wave = 32x64.
// C/D: col=lane&15, row=(lane>>4)*4+reg  [HW-verified m89/m91].
// ncols masks bias load + stores (for FO=40 padded to 64).
// ---------------------------------------------------------------------------
template <int K, bool BN, bool RELU, typename OT>
__global__ __launch_bounds__(256) void k_mfma(const __half* __restrict__ A,
                                              const __half* __restrict__ Wt,
                                              const float* __restrict__ cb,
                                              const float* __restrict__ g,
                                              const float* __restrict__ bb,
                                              const float* __restrict__ m,
                                              const float* __restrict__ vv,
                                              OT* __restrict__ Y, int ldy, int N, int ncols) {
    constexpr int KS = K / 32;
    constexpr int NCT = 4;  // 64 cols
    __shared__ __half bs[KS * NCT * 64 * 8];

    const int tid = threadIdx.x;
    const int col0 = blockIdx.y * 64;

    constexpr int PIECES = KS * NCT * 64;
#pragma unroll
    for (int p = tid; p < PIECES; p += 256) {
        int ks = p / (NCT * 64);
        int rem = p - ks * (NCT * 64);
        int ct = rem >> 6;
        int l = rem & 63;
        int col = col0 + ct * 16 + (l & 15);
        int kg = ks * 32 + (l >> 4) * 8;
        *(uint4*)&bs[p * 8] = *(const uint4*)&Wt[(size_t)col * K + kg];
    }
    __syncthreads();

    const int wave = tid >> 6;
    const int lane = tid & 63;
    const int rbase = blockIdx.x * 128 + wave * 32;
    const int r0 = rbase + (lane & 15);
    const int k0 = (lane >> 4) * 8;

    uint4 af[2][KS];
#pragma unroll
    for (int ks = 0; ks < KS; ++ks) {
        int kk = ks * 32 + k0;
        af[0][ks] = (r0 < N) ? *(const uint4*)&A[(size_t)r0 * K + kk] : uint4{0, 0, 0, 0};
        af[1][ks] = (r0 + 16 < N) ? *(const uint4*)&A[(size_t)(r0 + 16) * K + kk]
                                  : uint4{0, 0, 0, 0};
    }

    f32x4 acc[2][NCT];
#pragma unroll
    for (int rt = 0; rt < 2; ++rt)
#pragma unroll
        for (int ct = 0; ct < NCT; ++ct) acc[rt][ct] = {0.f, 0.f, 0.f, 0.f};

#pragma unroll
    for (int ks = 0; ks < KS; ++ks) {
        f16x8 b[NCT];
#pragma unroll
        for (int ct = 0; ct < NCT; ++ct)
            b[ct] = *(const f16x8*)&bs[((ks * NCT + ct) * 64 + lane) * 8];
#pragma unroll
        for (int rt = 0; rt < 2; ++rt) {
            f16x8 a = *(const f16x8*)&af[rt][ks];
#pragma unroll
            for (int ct = 0; ct < NCT; ++ct)
                acc[rt][ct] = __builtin_amdgcn_mfma_f32_16x16x32_f16(a, b[ct], acc[rt][ct], 0, 0, 0);
        }
    }

    const int cbase = col0 + (lane & 15);
#pragma unroll
    for (int ct = 0; ct < NCT; ++ct) {
        int col = cbase + ct * 16;
        if (col >= ncols) continue;
        float sc, sh;
        if (BN) {
            sc = g[col] * rsqrtf(vv[col] + 1e-5f);
            sh = bb[col] + (cb[col] - m[col]) * sc;
        } else {
            sc = 1.f;
            sh = cb[col];
        }
#pragma unroll
        for (int rt = 0; rt < 2; ++rt) {
#pragma unroll
            for (int r = 0; r < 4; ++r) {
                int row = rbase + rt * 16 + (lane >> 4) * 4 + r;
                if (row < N) {
                    float o = acc[rt][ct][r] * sc + sh;
                    if (RELU) o = fmaxf(o, 0.f);
                    if constexpr (sizeof(OT) == 2) {
                        Y[(size_t)row * ldy + col] = __float2half_rn(o);
                    } else {
                        Y[(size_t)row * ldy + col] = o;
                    }
                }
            }
        }
    }
}

extern "C" void kernel_launch(void* const* d_in, const int* in_sizes, int n_in,
                              void* d_out, int out_size, void* d_ws, size_t ws_size,
                              hipStream_t stream) {
    const float* x = (const float*)d_in[0];
    const int* ei = (const int*)d_in[1];
    const float* cw1 = (const float*)d_in[2];
    const float* cb1 = (const float*)d_in[3];
    const float* g1 = (const float*)d_in[4];
    const float* bb1 = (const float*)d_in[5];
    const float* m1 = (const float*)d_in[6];
    const float* v1 = (const float*)d_in[7];
    const float* cw2 = (const float*)d_in[8];
    const float* cb2 = (const float*)d_in[9];
    const float* g2 = (const float*)d_in[10];
    const float* bb2 = (const float*)d_in[11];
    const float* m2 = (const float*)d_in[12];
    const float* v2 = (const float*)d_in[13];
    const float* cw3 = (const float*)d_in[14];
    const float* cb3 = (const float*)d_in[15];
    const float* g3 = (const float*)d_in[16];
    const float* bb3 = (const float*)d_in[17];
    const float* m3 = (const float*)d_in[18];
    const float* v3 = (const float*)d_in[19];
    const float* lw1 = (const float*)d_in[20];
    const float* lb1 = (const float*)d_in[21];
    const float* lw2 = (const float*)d_in[22];
    const float* lb2 = (const float*)d_in[23];
    float* out = (float*)d_out;

    const int N = in_sizes[0] / 128;
    const int E = in_sizes[1] / 2;

    auto al = [](size_t v) { return (v + 255) & ~(size_t)255; };
    char* w = (char*)d_ws;
    size_t o = 0;
    float* dinv  = (float*)(w + o);  o = al(o + (size_t)N * 4);
    int* deg     = (int*)(w + o);    o = al(o + (size_t)N * 4);
    int* rowptr  = (int*)(w + o);    o = al(o + (size_t)(N + 1) * 4);
    int* part    = (int*)(w + o);    o = al(o + 1024 * 4);
    int* hist    = (int*)(w + o);    o = al(o + 2048 * 4);  // hist[1024] + hcur[1024]
    int* hcur    = hist + 1024;
    int* perm    = (int*)(w + o);    o = al(o + (size_t)N * 4);
    int* csr     = (int*)(w + o);    o = al(o + (size_t)E * 4);
    __half* XH   = (__half*)(w + o); o = al(o + (size_t)N * 128 * 2);
    __half* GH   = (__half*)(w + o); o = al(o + (size_t)N * 128 * 2);
    __half* H3h  = (__half*)(w + o); o = al(o + (size_t)N * 256 * 2);
    __half* Wt1  = (__half*)(w + o); o = al(o + (size_t)128 * 128 * 2);
    __half* Wt2  = (__half*)(w + o); o = al(o + (size_t)128 * 128 * 2);
    __half* Wt3  = (__half*)(w + o); o = al(o + (size_t)256 * 128 * 2);
    __half* Wt4  = (__half*)(w + o); o = al(o + (size_t)128 * 256 * 2);
    __half* Wt5  = (__half*)(w + o); o = al(o + (size_t)64 * 128 * 2);
    __half* Zh   = GH;  // lin1 output overlays GH (dead after conv3 GEMM)

    const int nb = cdiv(N, 256);

    // ---- CSR build + degree-sorted permutation ----
    k_zero_int<<<cdiv(N, 256), 256, 0, stream>>>(deg, N);
    k_deg<<<cdiv(E, 256), 256, 0, stream>>>(ei, E, deg);
    k_dinv<<<cdiv(N, 256), 256, 0, stream>>>(deg, dinv, N);
    k_scan1<<<nb, 256, 0, stream>>>(deg, part, N);
    k_scan2<<<1, 1024, 0, stream>>>(part, nb);
    k_scan3<<<nb, 256, 0, stream>>>(deg, part, rowptr, N);
    k_zero_int<<<cdiv(2048, 256), 256, 0, stream>>>(hist, 2048);
    k_hist<<<cdiv(N, 256), 256, 0, stream>>>(rowptr, hist, N);
    k_scan2<<<1, 1024, 0, stream>>>(hist, 1024);
    k_perm<<<cdiv(N, 256), 256, 0, stream>>>(rowptr, hist, hcur, perm, N);
    k_fill_csr<<<cdiv(E, 256), 256, 0, stream>>>(ei, E, rowptr, deg, csr);  // trashes deg

    // ---- conversions ----
    k_f2h<<<cdiv(N * 32, 256), 256, 0, stream>>>(x, XH, N * 32);
    k_wt<<<cdiv(128 * 128, 256), 256, 0, stream>>>(cw1, Wt1, 128, 128, 128);
    k_wt<<<cdiv(128 * 128, 256), 256, 0, stream>>>(cw2, Wt2, 128, 128, 128);
    k_wt<<<cdiv(256 * 128, 256), 256, 0, stream>>>(cw3, Wt3, 128, 256, 256);
    k_wt<<<cdiv(128 * 256, 256), 256, 0, stream>>>(lw1, Wt4, 256, 128, 128);
    k_wt<<<cdiv(64 * 128, 256), 256, 0, stream>>>(lw2, Wt5, 128, 40, 64);

    const int gx = cdiv(N, 128);

    // ---- conv1
    k_gather128<<<cdiv(N, 16), 256, 0, stream>>>(rowptr, csr, perm, dinv, XH, GH, N);
    k_mfma<128, true, true, __half><<<dim3(gx, 2), 256, 0, stream>>>(
        GH, Wt1, cb1, g1, bb1, m1, v1, XH, 128, N, 128);
    // ---- conv2
    k_gather128<<<cdiv(N, 16), 256, 0, stream>>>(rowptr, csr, perm, dinv, XH, GH, N);
    k_mfma<128, true, true, __half><<<dim3(gx, 2), 256, 0, stream>>>(
        GH, Wt2, cb2, g2, bb2, m2, v2, XH, 128, N, 128);
    // ---- conv3 (FO=256)
    k_gather128<<<cdiv(N, 16), 256, 0, stream>>>(rowptr, csr, perm, dinv, XH, GH, N);
    k_mfma<128, true, true, __half><<<dim3(gx, 4), 256, 0, stream>>>(
        GH, Wt3, cb3, g3, bb3, m3, v3, H3h, 256, N, 256);
    // ---- lin1: Zh = relu(H3h @ lw1 + lb1)
    k_mfma<256, false, true, __half><<<dim3(gx, 2), 256, 0, stream>>>(
        H3h, Wt4, lb1, nullptr, nullptr, nullptr, nullptr, Zh, 128, N, 128);
    // ---- lin2: out = Zh @ lw2 + lb2 (fp32, 40 cols)
    k_mfma<128, false, false, float><<<dim3(gx, 1), 256, 0, stream>>>(
        Zh, Wt5, lb2, nullptr, nullptr, nullptr, nullptr, out, 40, N, 40);
}

// Round 6
// 292.591 us; speedup vs baseline: 1.9049x; 1.9049x over previous
//
#include <hip/hip_runtime.h>
#include <hip/hip_fp16.h>

// ---------------------------------------------------------------------------
// DummyFairGCN R6: R4 structure + MFMA lin2 + countdown CSR fill.
// Degree-sort permutation REVERTED (k_perm atomic contention cost 134us).
// ---------------------------------------------------------------------------

typedef _Float16 f16x8 __attribute__((ext_vector_type(8)));
typedef float f32x4 __attribute__((ext_vector_type(4)));

static inline int cdiv(int a, int b) { return (a + b - 1) / b; }

__global__ __launch_bounds__(256) void k_zero_int(int* p, int n) {
    int i = blockIdx.x * 256 + threadIdx.x;
    if (i < n) p[i] = 0;
}

__global__ __launch_bounds__(256) void k_deg(const int* __restrict__ ei, int E, int* deg) {
    int i = blockIdx.x * 256 + threadIdx.x;
    if (i < E) atomicAdd(&deg[ei[E + i]], 1);
}

__global__ __launch_bounds__(256) void k_dinv(const int* __restrict__ deg, float* dinv, int n) {
    int i = blockIdx.x * 256 + threadIdx.x;
    if (i < n) dinv[i] = rsqrtf((float)(deg[i] + 1));  // +1 self-loop
}

// ---- exclusive scan of deg[N] -> rowptr[N+1] ----
__global__ __launch_bounds__(256) void k_scan1(const int* __restrict__ deg, int* part, int n) {
    __shared__ int s[256];
    int i = blockIdx.x * 256 + threadIdx.x;
    s[threadIdx.x] = (i < n) ? deg[i] : 0;
    __syncthreads();
#pragma unroll
    for (int off = 128; off > 0; off >>= 1) {
        if (threadIdx.x < off) s[threadIdx.x] += s[threadIdx.x + off];
        __syncthreads();
    }
    if (threadIdx.x == 0) part[blockIdx.x] = s[0];
}

__global__ void k_scan2(int* part, int nb) {  // single block, 1024 threads, in-place excl scan
    __shared__ int s[1024];
    int v = (threadIdx.x < nb) ? part[threadIdx.x] : 0;
    s[threadIdx.x] = v;
    __syncthreads();
    for (int off = 1; off < 1024; off <<= 1) {
        int t = (threadIdx.x >= (unsigned)off) ? s[threadIdx.x - off] : 0;
        __syncthreads();
        s[threadIdx.x] += t;
        __syncthreads();
    }
    if (threadIdx.x < nb) part[threadIdx.x] = s[threadIdx.x] - v;
}

__global__ __launch_bounds__(256) void k_scan3(const int* __restrict__ deg,
                                               const int* __restrict__ part,
                                               int* rowptr, int n) {
    __shared__ int s[256];
    int i = blockIdx.x * 256 + threadIdx.x;
    int v = (i < n) ? deg[i] : 0;
    s[threadIdx.x] = v;
    __syncthreads();
    for (int off = 1; off < 256; off <<= 1) {
        int t = (threadIdx.x >= (unsigned)off) ? s[threadIdx.x - off] : 0;
        __syncthreads();
        s[threadIdx.x] += t;
        __syncthreads();
    }
    int excl = part[blockIdx.x] + s[threadIdx.x] - v;
    if (i < n) rowptr[i] = excl;
    if (i == n - 1) rowptr[n] = excl + v;
}

// countdown fill: destroys deg (ends all-zero)
__global__ __launch_bounds__(256) void k_fill_csr(const int* __restrict__ ei, int E,
                                                  const int* __restrict__ rowptr,
                                                  int* deg, int* csr) {
    int e = blockIdx.x * 256 + threadIdx.x;
    if (e >= E) return;
    int src = ei[e];
    int dst = ei[E + e];
    int p = rowptr[dst] + atomicSub(&deg[dst], 1) - 1;
    __builtin_nontemporal_store(src, &csr[p]);
}

__global__ __launch_bounds__(256) void k_f2h(const float* __restrict__ x, __half* __restrict__ y,
                                             int n4) {
    int i = blockIdx.x * 256 + threadIdx.x;
    if (i >= n4) return;
    float4 v = ((const float4*)x)[i];
    __half h[4] = {__float2half_rn(v.x), __float2half_rn(v.y), __float2half_rn(v.z),
                   __float2half_rn(v.w)};
    ((uint2*)y)[i] = *(uint2*)h;
}

// W[K x FO] fp32 -> Wt[FOP x K] fp16, zero-padded to FOP cols
__global__ __launch_bounds__(256) void k_wt(const float* __restrict__ W, __half* __restrict__ Wt,
                                            int K, int FO, int FOP) {
    int i = blockIdx.x * 256 + threadIdx.x;
    if (i >= FOP * K) return;
    int c = i / K;
    int k = i - c * K;
    Wt[i] = (c < FO) ? __float2half_rn(W[(size_t)k * FO + c]) : __half(0.f);
}

__device__ inline void unpack8(uint4 v, float* f) {
    __half2* h = (__half2*)&v;
#pragma unroll
    for (int i = 0; i < 4; ++i) {
        float2 t = __half22float2(h[i]);
        f[2 * i] = t.x;
        f[2 * i + 1] = t.y;
    }
}

// CSR gather over 128-wide fp16 rows -> fp16 out (fp32 accum).
// Identity node order; 16 lanes/node, 16B/lane, 8-edge unroll.
__global__ __launch_bounds__(256) void k_gather128(const int* __restrict__ rowptr,
                                                   const int* __restrict__ csr,
                                                   const float* __restrict__ dinv,
                                                   const __half* __restrict__ xh,
                                                   __half* __restrict__ G, int N) {
    int t = blockIdx.x * 256 + threadIdx.x;
    int node = t >> 4;
    if (node >= N) return;
    int lane = t & 15;
    const uint4* xb = (const uint4*)xh;  // 16 uint4 per row
    float di = dinv[node];
    float acc[8];
    {
        uint4 v = xb[(size_t)node * 16 + lane];
        float f[8];
        unpack8(v, f);
        float s = di * di;
#pragma unroll
        for (int j = 0; j < 8; ++j) acc[j] = s * f[j];
    }
    int p0 = rowptr[node], p1 = rowptr[node + 1];
    int p = p0;
    for (; p + 8 <= p1; p += 8) {
        int s_[8];
        float wg[8];
        uint4 v[8];
#pragma unroll
        for (int j = 0; j < 8; ++j) s_[j] = csr[p + j];
#pragma unroll
        for (int j = 0; j < 8; ++j) wg[j] = di * dinv[s_[j]];
#pragma unroll
        for (int j = 0; j < 8; ++j) v[j] = xb[(size_t)s_[j] * 16 + lane];
#pragma unroll
        for (int j = 0; j < 8; ++j) {
            float f[8];
            unpack8(v[j], f);
#pragma unroll
            for (int k = 0; k < 8; ++k) acc[k] += wg[j] * f[k];
        }
    }
    for (; p + 4 <= p1; p += 4) {
        int s_[4];
        float wg[4];
        uint4 v[4];
#pragma unroll
        for (int j = 0; j < 4; ++j) s_[j] = csr[p + j];
#pragma unroll
        for (int j = 0; j < 4; ++j) wg[j] = di * dinv[s_[j]];
#pragma unroll
        for (int j = 0; j < 4; ++j) v[j] = xb[(size_t)s_[j] * 16 + lane];
#pragma unroll
        for (int j = 0; j < 4; ++j) {
            float f[8];
            unpack8(v[j], f);
#pragma unroll
            for (int k = 0; k < 8; ++k) acc[k] += wg[j] * f[k];
        }
    }
    for (; p < p1; ++p) {
        int src = csr[p];
        float w = di * dinv[src];
        uint4 v = xb[(size_t)src * 16 + lane];
        float f[8];
        unpack8(v, f);
#pragma unroll
        for (int j = 0; j < 8; ++j) acc[j] += w * f[j];
    }
    __half hh[8];
#pragma unroll
    for (int j = 0; j < 8; ++j) hh[j] = __float2half_rn(acc[j]);
    *(uint4*)&G[(size_t)node * 128 + lane * 8] = *(uint4*)hh;
}

// ---------------------------------------------------------------------------
// MFMA fp16 GEMM, fused epilogue (BN+ReLU / bias+ReLU / bias).
// Block = 4 waves; tile 128 rows x 64 cols; wave = 32x64.
// C/D: col=lane&15, row=(lane>>4)*4+reg  [HW-verified m89/m91].
// ncols masks bias load + stores (for FO=40 padded to 64).
// ---------------------------------------------------------------------------
template <int K, bool BN, bool RELU, typename OT>
__global__ __launch_bounds__(256) void k_mfma(const __half* __restrict__ A,
                                              const __half* __restrict__ Wt,
                                              const float* __restrict__ cb,
                                              const float* __restrict__ g,
                                              const float* __restrict__ bb,
                                              const float* __restrict__ m,
                                              const float* __restrict__ vv,
                                              OT* __restrict__ Y, int ldy, int N, int ncols) {
    constexpr int KS = K / 32;
    constexpr int NCT = 4;  // 64 cols
    __shared__ __half bs[KS * NCT * 64 * 8];

    const int tid = threadIdx.x;
    const int col0 = blockIdx.y * 64;

    constexpr int PIECES = KS * NCT * 64;
#pragma unroll
    for (int p = tid; p < PIECES; p += 256) {
        int ks = p / (NCT * 64);
        int rem = p - ks * (NCT * 64);
        int ct = rem >> 6;
        int l = rem & 63;
        int col = col0 + ct * 16 + (l & 15);
        int kg = ks * 32 + (l >> 4) * 8;
        *(uint4*)&bs[p * 8] = *(const uint4*)&Wt[(size_t)col * K + kg];
    }
    __syncthreads();

    const int wave = tid >> 6;
    const int lane = tid & 63;
    const int rbase = blockIdx.x * 128 + wave * 32;
    const int r0 = rbase + (lane & 15);
    const int k0 = (lane >> 4) * 8;

    uint4 af[2][KS];
#pragma unroll
    for (int ks = 0; ks < KS; ++ks) {
        int kk = ks * 32 + k0;
        af[0][ks] = (r0 < N) ? *(const uint4*)&A[(size_t)r0 * K + kk] : uint4{0, 0, 0, 0};
        af[1][ks] = (r0 + 16 < N) ? *(const uint4*)&A[(size_t)(r0 + 16) * K + kk]
                                  : uint4{0, 0, 0, 0};
    }

    f32x4 acc[2][NCT];
#pragma unroll
    for (int rt = 0; rt < 2; ++rt)
#pragma unroll
        for (int ct = 0; ct < NCT; ++ct) acc[rt][ct] = {0.f, 0.f, 0.f, 0.f};

#pragma unroll
    for (int ks = 0; ks < KS; ++ks) {
        f16x8 b[NCT];
#pragma unroll
        for (int ct = 0; ct < NCT; ++ct)
            b[ct] = *(const f16x8*)&bs[((ks * NCT + ct) * 64 + lane) * 8];
#pragma unroll
        for (int rt = 0; rt < 2; ++rt) {
            f16x8 a = *(const f16x8*)&af[rt][ks];
#pragma unroll
            for (int ct = 0; ct < NCT; ++ct)
                acc[rt][ct] = __builtin_amdgcn_mfma_f32_16x16x32_f16(a, b[ct], acc[rt][ct], 0, 0, 0);
        }
    }

    const int cbase = col0 + (lane & 15);
#pragma unroll
    for (int ct = 0; ct < NCT; ++ct) {
        int col = cbase + ct * 16;
        if (col >= ncols) continue;
        float sc, sh;
        if (BN) {
            sc = g[col] * rsqrtf(vv[col] + 1e-5f);
            sh = bb[col] + (cb[col] - m[col]) * sc;
        } else {
            sc = 1.f;
            sh = cb[col];
        }
#pragma unroll
        for (int rt = 0; rt < 2; ++rt) {
#pragma unroll
            for (int r = 0; r < 4; ++r) {
                int row = rbase + rt * 16 + (lane >> 4) * 4 + r;
                if (row < N) {
                    float o = acc[rt][ct][r] * sc + sh;
                    if (RELU) o = fmaxf(o, 0.f);
                    if constexpr (sizeof(OT) == 2) {
                        Y[(size_t)row * ldy + col] = __float2half_rn(o);
                    } else {
                        Y[(size_t)row * ldy + col] = o;
                    }
                }
            }
        }
    }
}

extern "C" void kernel_launch(void* const* d_in, const int* in_sizes, int n_in,
                              void* d_out, int out_size, void* d_ws, size_t ws_size,
                              hipStream_t stream) {
    const float* x = (const float*)d_in[0];
    const int* ei = (const int*)d_in[1];
    const float* cw1 = (const float*)d_in[2];
    const float* cb1 = (const float*)d_in[3];
    const float* g1 = (const float*)d_in[4];
    const float* bb1 = (const float*)d_in[5];
    const float* m1 = (const float*)d_in[6];
    const float* v1 = (const float*)d_in[7];
    const float* cw2 = (const float*)d_in[8];
    const float* cb2 = (const float*)d_in[9];
    const float* g2 = (const float*)d_in[10];
    const float* bb2 = (const float*)d_in[11];
    const float* m2 = (const float*)d_in[12];
    const float* v2 = (const float*)d_in[13];
    const float* cw3 = (const float*)d_in[14];
    const float* cb3 = (const float*)d_in[15];
    const float* g3 = (const float*)d_in[16];
    const float* bb3 = (const float*)d_in[17];
    const float* m3 = (const float*)d_in[18];
    const float* v3 = (const float*)d_in[19];
    const float* lw1 = (const float*)d_in[20];
    const float* lb1 = (const float*)d_in[21];
    const float* lw2 = (const float*)d_in[22];
    const float* lb2 = (const float*)d_in[23];
    float* out = (float*)d_out;

    const int N = in_sizes[0] / 128;
    const int E = in_sizes[1] / 2;

    auto al = [](size_t v) { return (v + 255) & ~(size_t)255; };
    char* w = (char*)d_ws;
    size_t o = 0;
    float* dinv  = (float*)(w + o);  o = al(o + (size_t)N * 4);
    int* deg     = (int*)(w + o);    o = al(o + (size_t)N * 4);
    int* rowptr  = (int*)(w + o);    o = al(o + (size_t)(N + 1) * 4);
    int* part    = (int*)(w + o);    o = al(o + 1024 * 4);
    int* csr     = (int*)(w + o);    o = al(o + (size_t)E * 4);
    __half* XH   = (__half*)(w + o); o = al(o + (size_t)N * 128 * 2);
    __half* GH   = (__half*)(w + o); o = al(o + (size_t)N * 128 * 2);
    __half* H3h  = (__half*)(w + o); o = al(o + (size_t)N * 256 * 2);
    __half* Wt1  = (__half*)(w + o); o = al(o + (size_t)128 * 128 * 2);
    __half* Wt2  = (__half*)(w + o); o = al(o + (size_t)128 * 128 * 2);
    __half* Wt3  = (__half*)(w + o); o = al(o + (size_t)256 * 128 * 2);
    __half* Wt4  = (__half*)(w + o); o = al(o + (size_t)128 * 256 * 2);
    __half* Wt5  = (__half*)(w + o); o = al(o + (size_t)64 * 128 * 2);
    __half* Zh   = GH;  // lin1 output overlays GH (dead after conv3 GEMM)

    const int nb = cdiv(N, 256);

    // ---- CSR build ----
    k_zero_int<<<cdiv(N, 256), 256, 0, stream>>>(deg, N);
    k_deg<<<cdiv(E, 256), 256, 0, stream>>>(ei, E, deg);
    k_dinv<<<cdiv(N, 256), 256, 0, stream>>>(deg, dinv, N);
    k_scan1<<<nb, 256, 0, stream>>>(deg, part, N);
    k_scan2<<<1, 1024, 0, stream>>>(part, nb);
    k_scan3<<<nb, 256, 0, stream>>>(deg, part, rowptr, N);
    k_fill_csr<<<cdiv(E, 256), 256, 0, stream>>>(ei, E, rowptr, deg, csr);  // trashes deg

    // ---- conversions ----
    k_f2h<<<cdiv(N * 32, 256), 256, 0, stream>>>(x, XH, N * 32);
    k_wt<<<cdiv(128 * 128, 256), 256, 0, stream>>>(cw1, Wt1, 128, 128, 128);
    k_wt<<<cdiv(128 * 128, 256), 256, 0, stream>>>(cw2, Wt2, 128, 128, 128);
    k_wt<<<cdiv(256 * 128, 256), 256, 0, stream>>>(cw3, Wt3, 128, 256, 256);
    k_wt<<<cdiv(128 * 256, 256), 256, 0, stream>>>(lw1, Wt4, 256, 128, 128);
    k_wt<<<cdiv(64 * 128, 256), 256, 0, stream>>>(lw2, Wt5, 128, 40, 64);

    const int gx = cdiv(N, 128);

    // ---- conv1
    k_gather128<<<cdiv(N, 16), 256, 0, stream>>>(rowptr, csr, dinv, XH, GH, N);
    k_mfma<128, true, true, __half><<<dim3(gx, 2), 256, 0, stream>>>(
        GH, Wt1, cb1, g1, bb1, m1, v1, XH, 128, N, 128);
    // ---- conv2
    k_gather128<<<cdiv(N, 16), 256, 0, stream>>>(rowptr, csr, dinv, XH, GH, N);
    k_mfma<128, true, true, __half><<<dim3(gx, 2), 256, 0, stream>>>(
        GH, Wt2, cb2, g2, bb2, m2, v2, XH, 128, N, 128);
    // ---- conv3 (FO=256)
    k_gather128<<<cdiv(N, 16), 256, 0, stream>>>(rowptr, csr, dinv, XH, GH, N);
    k_mfma<128, true, true, __half><<<dim3(gx, 4), 256, 0, stream>>>(
        GH, Wt3, cb3, g3, bb3, m3, v3, H3h, 256, N, 256);
    // ---- lin1: Zh = relu(H3h @ lw1 + lb1)
    k_mfma<256, false, true, __half><<<dim3(gx, 2), 256, 0, stream>>>(
        H3h, Wt4, lb1, nullptr, nullptr, nullptr, nullptr, Zh, 128, N, 128);
    // ---- lin2: out = Zh @ lw2 + lb2 (fp32, 40 cols)
    k_mfma<128, false, false, float><<<dim3(gx, 1), 256, 0, stream>>>(
        Zh, Wt5, lb2, nullptr, nullptr, nullptr, nullptr, out, 40, N, 40);
}

// Round 7
// 283.770 us; speedup vs baseline: 1.9641x; 1.0311x over previous
//
#include <hip/hip_runtime.h>
#include <hip/hip_fp16.h>

// ---------------------------------------------------------------------------
// DummyFairGCN R7: R6 + (a) plain store in fill_csr (nt-store was 32B-granule
// write amplification into L2-resident csr), (b) 64-lane/node gather (zero
// intra-wave degree divergence; was ~26% waste at 16 lanes/node).
// ---------------------------------------------------------------------------

typedef _Float16 f16x8 __attribute__((ext_vector_type(8)));
typedef float f32x4 __attribute__((ext_vector_type(4)));

static inline int cdiv(int a, int b) { return (a + b - 1) / b; }

__global__ __launch_bounds__(256) void k_zero_int(int* p, int n) {
    int i = blockIdx.x * 256 + threadIdx.x;
    if (i < n) p[i] = 0;
}

__global__ __launch_bounds__(256) void k_deg(const int* __restrict__ ei, int E, int* deg) {
    int i = blockIdx.x * 256 + threadIdx.x;
    if (i < E) atomicAdd(&deg[ei[E + i]], 1);
}

__global__ __launch_bounds__(256) void k_dinv(const int* __restrict__ deg, float* dinv, int n) {
    int i = blockIdx.x * 256 + threadIdx.x;
    if (i < n) dinv[i] = rsqrtf((float)(deg[i] + 1));  // +1 self-loop
}

// ---- exclusive scan of deg[N] -> rowptr[N+1] ----
__global__ __launch_bounds__(256) void k_scan1(const int* __restrict__ deg, int* part, int n) {
    __shared__ int s[256];
    int i = blockIdx.x * 256 + threadIdx.x;
    s[threadIdx.x] = (i < n) ? deg[i] : 0;
    __syncthreads();
#pragma unroll
    for (int off = 128; off > 0; off >>= 1) {
        if (threadIdx.x < off) s[threadIdx.x] += s[threadIdx.x + off];
        __syncthreads();
    }
    if (threadIdx.x == 0) part[blockIdx.x] = s[0];
}

__global__ void k_scan2(int* part, int nb) {  // single block, 1024 threads, in-place excl scan
    __shared__ int s[1024];
    int v = (threadIdx.x < nb) ? part[threadIdx.x] : 0;
    s[threadIdx.x] = v;
    __syncthreads();
    for (int off = 1; off < 1024; off <<= 1) {
        int t = (threadIdx.x >= (unsigned)off) ? s[threadIdx.x - off] : 0;
        __syncthreads();
        s[threadIdx.x] += t;
        __syncthreads();
    }
    if (threadIdx.x < nb) part[threadIdx.x] = s[threadIdx.x] - v;
}

__global__ __launch_bounds__(256) void k_scan3(const int* __restrict__ deg,
                                               const int* __restrict__ part,
                                               int* rowptr, int n) {
    __shared__ int s[256];
    int i = blockIdx.x * 256 + threadIdx.x;
    int v = (i < n) ? deg[i] : 0;
    s[threadIdx.x] = v;
    __syncthreads();
    for (int off = 1; off < 256; off <<= 1) {
        int t = (threadIdx.x >= (unsigned)off) ? s[threadIdx.x - off] : 0;
        __syncthreads();
        s[threadIdx.x] += t;
        __syncthreads();
    }
    int excl = part[blockIdx.x] + s[threadIdx.x] - v;
    if (i < n) rowptr[i] = excl;
    if (i == n - 1) rowptr[n] = excl + v;
}

// countdown fill: destroys deg (ends all-zero); plain store (csr is L2-resident)
__global__ __launch_bounds__(256) void k_fill_csr(const int* __restrict__ ei, int E,
                                                  const int* __restrict__ rowptr,
                                                  int* deg, int* csr) {
    int e = blockIdx.x * 256 + threadIdx.x;
    if (e >= E) return;
    int src = ei[e];
    int dst = ei[E + e];
    int p = rowptr[dst] + atomicSub(&deg[dst], 1) - 1;
    csr[p] = src;
}

__global__ __launch_bounds__(256) void k_f2h(const float* __restrict__ x, __half* __restrict__ y,
                                             int n4) {
    int i = blockIdx.x * 256 + threadIdx.x;
    if (i >= n4) return;
    float4 v = ((const float4*)x)[i];
    __half h[4] = {__float2half_rn(v.x), __float2half_rn(v.y), __float2half_rn(v.z),
                   __float2half_rn(v.w)};
    ((uint2*)y)[i] = *(uint2*)h;
}

// W[K x FO] fp32 -> Wt[FOP x K] fp16, zero-padded to FOP cols
__global__ __launch_bounds__(256) void k_wt(const float* __restrict__ W, __half* __restrict__ Wt,
                                            int K, int FO, int FOP) {
    int i = blockIdx.x * 256 + threadIdx.x;
    if (i >= FOP * K) return;
    int c = i / K;
    int k = i - c * K;
    Wt[i] = (c < FO) ? __float2half_rn(W[(size_t)k * FO + c]) : __half(0.f);
}

// CSR gather over 128-wide fp16 rows -> fp16 out (fp32 accum).
// 64 lanes per node (one wave), 4B (__half2) per lane per edge, 8-edge unroll.
// Zero intra-wave degree divergence; csr/dinv loads are wave-uniform.
__global__ __launch_bounds__(256) void k_gather64(const int* __restrict__ rowptr,
                                                  const int* __restrict__ csr,
                                                  const float* __restrict__ dinv,
                                                  const __half* __restrict__ xh,
                                                  __half* __restrict__ G, int N) {
    int t = blockIdx.x * 256 + threadIdx.x;
    int node = t >> 6;
    if (node >= N) return;
    int lane = t & 63;
    const __half2* xb = (const __half2*)xh;  // 64 half2 per row
    float di = dinv[node];
    float ax, ay;
    {
        float2 f = __half22float2(xb[(size_t)node * 64 + lane]);
        float s = di * di;
        ax = s * f.x;
        ay = s * f.y;
    }
    int p0 = rowptr[node], p1 = rowptr[node + 1];
    int p = p0;
    for (; p + 8 <= p1; p += 8) {
        int s_[8];
        float wg[8];
        __half2 v[8];
#pragma unroll
        for (int j = 0; j < 8; ++j) s_[j] = csr[p + j];
#pragma unroll
        for (int j = 0; j < 8; ++j) wg[j] = di * dinv[s_[j]];
#pragma unroll
        for (int j = 0; j < 8; ++j) v[j] = xb[(size_t)s_[j] * 64 + lane];
#pragma unroll
        for (int j = 0; j < 8; ++j) {
            float2 f = __half22float2(v[j]);
            ax += wg[j] * f.x;
            ay += wg[j] * f.y;
        }
    }
    for (; p + 4 <= p1; p += 4) {
        int s_[4];
        float wg[4];
        __half2 v[4];
#pragma unroll
        for (int j = 0; j < 4; ++j) s_[j] = csr[p + j];
#pragma unroll
        for (int j = 0; j < 4; ++j) wg[j] = di * dinv[s_[j]];
#pragma unroll
        for (int j = 0; j < 4; ++j) v[j] = xb[(size_t)s_[j] * 64 + lane];
#pragma unroll
        for (int j = 0; j < 4; ++j) {
            float2 f = __half22float2(v[j]);
            ax += wg[j] * f.x;
            ay += wg[j] * f.y;
        }
    }
    for (; p < p1; ++p) {
        int src = csr[p];
        float w = di * dinv[src];
        float2 f = __half22float2(xb[(size_t)src * 64 + lane]);
        ax += w * f.x;
        ay += w * f.y;
    }
    ((__half2*)G)[(size_t)node * 64 + lane] = __floats2half2_rn(ax, ay);
}

// ---------------------------------------------------------------------------
// MFMA fp16 GEMM, fused epilogue (BN+ReLU / bias+ReLU / bias).
// Block = 4 waves; tile 128 rows x 64 cols; wave = 32x64.
// C/D: col=lane&15, row=(lane>>4)*4+reg  [HW-verified m89/m91].
// ncols masks bias load + stores (for FO=40 padded to 64).
// ---------------------------------------------------------------------------
template <int K, bool BN, bool RELU, typename OT>
__global__ __launch_bounds__(256) void k_mfma(const __half* __restrict__ A,
                                              const __half* __restrict__ Wt,
                                              const float* __restrict__ cb,
                                              const float* __restrict__ g,
                                              const float* __restrict__ bb,
                                              const float* __restrict__ m,
                                              const float* __restrict__ vv,
                                              OT* __restrict__ Y, int ldy, int N, int ncols) {
    constexpr int KS = K / 32;
    constexpr int NCT = 4;  // 64 cols
    __shared__ __half bs[KS * NCT * 64 * 8];

    const int tid = threadIdx.x;
    const int col0 = blockIdx.y * 64;

    constexpr int PIECES = KS * NCT * 64;
#pragma unroll
    for (int p = tid; p < PIECES; p += 256) {
        int ks = p / (NCT * 64);
        int rem = p - ks * (NCT * 64);
        int ct = rem >> 6;
        int l = rem & 63;
        int col = col0 + ct * 16 + (l & 15);
        int kg = ks * 32 + (l >> 4) * 8;
        *(uint4*)&bs[p * 8] = *(const uint4*)&Wt[(size_t)col * K + kg];
    }
    __syncthreads();

    const int wave = tid >> 6;
    const int lane = tid & 63;
    const int rbase = blockIdx.x * 128 + wave * 32;
    const int r0 = rbase + (lane & 15);
    const int k0 = (lane >> 4) * 8;

    uint4 af[2][KS];
#pragma unroll
    for (int ks = 0; ks < KS; ++ks) {
        int kk = ks * 32 + k0;
        af[0][ks] = (r0 < N) ? *(const uint4*)&A[(size_t)r0 * K + kk] : uint4{0, 0, 0, 0};
        af[1][ks] = (r0 + 16 < N) ? *(const uint4*)&A[(size_t)(r0 + 16) * K + kk]
                                  : uint4{0, 0, 0, 0};
    }

    f32x4 acc[2][NCT];
#pragma unroll
    for (int rt = 0; rt < 2; ++rt)
#pragma unroll
        for (int ct = 0; ct < NCT; ++ct) acc[rt][ct] = {0.f, 0.f, 0.f, 0.f};

#pragma unroll
    for (int ks = 0; ks < KS; ++ks) {
        f16x8 b[NCT];
#pragma unroll
        for (int ct = 0; ct < NCT; ++ct)
            b[ct] = *(const f16x8*)&bs[((ks * NCT + ct) * 64 + lane) * 8];
#pragma unroll
        for (int rt = 0; rt < 2; ++rt) {
            f16x8 a = *(const f16x8*)&af[rt][ks];
#pragma unroll
            for (int ct = 0; ct < NCT; ++ct)
                acc[rt][ct] = __builtin_amdgcn_mfma_f32_16x16x32_f16(a, b[ct], acc[rt][ct], 0, 0, 0);
        }
    }

    const int cbase = col0 + (lane & 15);
#pragma unroll
    for (int ct = 0; ct < NCT; ++ct) {
        int col = cbase + ct * 16;
        if (col >= ncols) continue;
        float sc, sh;
        if (BN) {
            sc = g[col] * rsqrtf(vv[col] + 1e-5f);
            sh = bb[col] + (cb[col] - m[col]) * sc;
        } else {
            sc = 1.f;
            sh = cb[col];
        }
#pragma unroll
        for (int rt = 0; rt < 2; ++rt) {
#pragma unroll
            for (int r = 0; r < 4; ++r) {
                int row = rbase + rt * 16 + (lane >> 4) * 4 + r;
                if (row < N) {
                    float o = acc[rt][ct][r] * sc + sh;
                    if (RELU) o = fmaxf(o, 0.f);
                    if constexpr (sizeof(OT) == 2) {
                        Y[(size_t)row * ldy + col] = __float2half_rn(o);
                    } else {
                        Y[(size_t)row * ldy + col] = o;
                    }
                }
            }
        }
    }
}

extern "C" void kernel_launch(void* const* d_in, const int* in_sizes, int n_in,
                              void* d_out, int out_size, void* d_ws, size_t ws_size,
                              hipStream_t stream) {
    const float* x = (const float*)d_in[0];
    const int* ei = (const int*)d_in[1];
    const float* cw1 = (const float*)d_in[2];
    const float* cb1 = (const float*)d_in[3];
    const float* g1 = (const float*)d_in[4];
    const float* bb1 = (const float*)d_in[5];
    const float* m1 = (const float*)d_in[6];
    const float* v1 = (const float*)d_in[7];
    const float* cw2 = (const float*)d_in[8];
    const float* cb2 = (const float*)d_in[9];
    const float* g2 = (const float*)d_in[10];
    const float* bb2 = (const float*)d_in[11];
    const float* m2 = (const float*)d_in[12];
    const float* v2 = (const float*)d_in[13];
    const float* cw3 = (const float*)d_in[14];
    const float* cb3 = (const float*)d_in[15];
    const float* g3 = (const float*)d_in[16];
    const float* bb3 = (const float*)d_in[17];
    const float* m3 = (const float*)d_in[18];
    const float* v3 = (const float*)d_in[19];
    const float* lw1 = (const float*)d_in[20];
    const float* lb1 = (const float*)d_in[21];
    const float* lw2 = (const float*)d_in[22];
    const float* lb2 = (const float*)d_in[23];
    float* out = (float*)d_out;

    const int N = in_sizes[0] / 128;
    const int E = in_sizes[1] / 2;

    auto al = [](size_t v) { return (v + 255) & ~(size_t)255; };
    char* w = (char*)d_ws;
    size_t o = 0;
    float* dinv  = (float*)(w + o);  o = al(o + (size_t)N * 4);
    int* deg     = (int*)(w + o);    o = al(o + (size_t)N * 4);
    int* rowptr  = (int*)(w + o);    o = al(o + (size_t)(N + 1) * 4);
    int* part    = (int*)(w + o);    o = al(o + 1024 * 4);
    int* csr     = (int*)(w + o);    o = al(o + (size_t)E * 4);
    __half* XH   = (__half*)(w + o); o = al(o + (size_t)N * 128 * 2);
    __half* GH   = (__half*)(w + o); o = al(o + (size_t)N * 128 * 2);
    __half* H3h  = (__half*)(w + o); o = al(o + (size_t)N * 256 * 2);
    __half* Wt1  = (__half*)(w + o); o = al(o + (size_t)128 * 128 * 2);
    __half* Wt2  = (__half*)(w + o); o = al(o + (size_t)128 * 128 * 2);
    __half* Wt3  = (__half*)(w + o); o = al(o + (size_t)256 * 128 * 2);
    __half* Wt4  = (__half*)(w + o); o = al(o + (size_t)128 * 256 * 2);
    __half* Wt5  = (__half*)(w + o); o = al(o + (size_t)64 * 128 * 2);
    __half* Zh   = GH;  // lin1 output overlays GH (dead after conv3 GEMM)

    const int nb = cdiv(N, 256);

    // ---- CSR build ----
    k_zero_int<<<cdiv(N, 256), 256, 0, stream>>>(deg, N);
    k_deg<<<cdiv(E, 256), 256, 0, stream>>>(ei, E, deg);
    k_dinv<<<cdiv(N, 256), 256, 0, stream>>>(deg, dinv, N);
    k_scan1<<<nb, 256, 0, stream>>>(deg, part, N);
    k_scan2<<<1, 1024, 0, stream>>>(part, nb);
    k_scan3<<<nb, 256, 0, stream>>>(deg, part, rowptr, N);
    k_fill_csr<<<cdiv(E, 256), 256, 0, stream>>>(ei, E, rowptr, deg, csr);  // trashes deg

    // ---- conversions ----
    k_f2h<<<cdiv(N * 32, 256), 256, 0, stream>>>(x, XH, N * 32);
    k_wt<<<cdiv(128 * 128, 256), 256, 0, stream>>>(cw1, Wt1, 128, 128, 128);
    k_wt<<<cdiv(128 * 128, 256), 256, 0, stream>>>(cw2, Wt2, 128, 128, 128);
    k_wt<<<cdiv(256 * 128, 256), 256, 0, stream>>>(cw3, Wt3, 128, 256, 256);
    k_wt<<<cdiv(128 * 256, 256), 256, 0, stream>>>(lw1, Wt4, 256, 128, 128);
    k_wt<<<cdiv(64 * 128, 256), 256, 0, stream>>>(lw2, Wt5, 128, 40, 64);

    const int gx = cdiv(N, 128);

    // ---- conv1
    k_gather64<<<cdiv(N, 4), 256, 0, stream>>>(rowptr, csr, dinv, XH, GH, N);
    k_mfma<128, true, true, __half><<<dim3(gx, 2), 256, 0, stream>>>(
        GH, Wt1, cb1, g1, bb1, m1, v1, XH, 128, N, 128);
    // ---- conv2
    k_gather64<<<cdiv(N, 4), 256, 0, stream>>>(rowptr, csr, dinv, XH, GH, N);
    k_mfma<128, true, true, __half><<<dim3(gx, 2), 256, 0, stream>>>(
        GH, Wt2, cb2, g2, bb2, m2, v2, XH, 128, N, 128);
    // ---- conv3 (FO=256)
    k_gather64<<<cdiv(N, 4), 256, 0, stream>>>(rowptr, csr, dinv, XH, GH, N);
    k_mfma<128, true, true, __half><<<dim3(gx, 4), 256, 0, stream>>>(
        GH, Wt3, cb3, g3, bb3, m3, v3, H3h, 256, N, 256);
    // ---- lin1: Zh = relu(H3h @ lw1 + lb1)
    k_mfma<256, false, true, __half><<<dim3(gx, 2), 256, 0, stream>>>(
        H3h, Wt4, lb1, nullptr, nullptr, nullptr, nullptr, Zh, 128, N, 128);
    // ---- lin2: out = Zh @ lw2 + lb2 (fp32, 40 cols)
    k_mfma<128, false, false, float><<<dim3(gx, 1), 256, 0, stream>>>(
        Zh, Wt5, lb2, nullptr, nullptr, nullptr, nullptr, out, 40, N, 40);
}

// Round 8
// 223.504 us; speedup vs baseline: 2.4937x; 1.2696x over previous
//
#include <hip/hip_runtime.h>
#include <hip/hip_fp16.h>

// ---------------------------------------------------------------------------
// DummyFairGCN R8: bucketed counting-sort CSR build (LDS atomics; no 50k-way
// global atomic histogram), fused weight conversions, R7 gather/MFMA pipeline.
// ---------------------------------------------------------------------------

typedef _Float16 f16x8 __attribute__((ext_vector_type(8)));
typedef float f32x4 __attribute__((ext_vector_type(4)));

static inline int cdiv(int a, int b) { return (a + b - 1) / b; }

__global__ __launch_bounds__(256) void k_zero_int(int* p, int n) {
    int i = blockIdx.x * 256 + threadIdx.x;
    if (i < n) p[i] = 0;
}

// ---- Pass A: per-block bucket histogram; reserve contiguous ranges ----
__global__ __launch_bounds__(256) void k_bcount(const int* __restrict__ ei, int E,
                                                int* bucketCount, int* blockBase) {
    __shared__ int lh[256];
    lh[threadIdx.x] = 0;
    __syncthreads();
    int base = blockIdx.x * 2048;
#pragma unroll
    for (int i = 0; i < 8; ++i) {
        int e = base + i * 256 + threadIdx.x;
        if (e < E) atomicAdd(&lh[ei[E + e] >> 8], 1);
    }
    __syncthreads();
    blockBase[blockIdx.x * 256 + threadIdx.x] =
        atomicAdd(&bucketCount[threadIdx.x], lh[threadIdx.x]);
}

// ---- bucket exclusive scan (single block); also rowptr[N]=E ----
__global__ void k_bscan(const int* __restrict__ bucketCount, int* bucketPtr, int nbk,
                        int* rowptr, int N, int E) {
    __shared__ int s[1024];
    int v = (threadIdx.x < nbk) ? bucketCount[threadIdx.x] : 0;
    s[threadIdx.x] = v;
    __syncthreads();
    for (int off = 1; off < 1024; off <<= 1) {
        int t = (threadIdx.x >= (unsigned)off) ? s[threadIdx.x - off] : 0;
        __syncthreads();
        s[threadIdx.x] += t;
        __syncthreads();
    }
    if (threadIdx.x < nbk) bucketPtr[threadIdx.x] = s[threadIdx.x] - v;
    if (threadIdx.x == 0) {
        bucketPtr[nbk] = E;
        rowptr[N] = E;
    }
}

// ---- Pass B: scatter edges into bucket-ordered ebuf (contiguous runs) ----
__global__ __launch_bounds__(256) void k_bscatter(const int* __restrict__ ei, int E,
                                                  const int* __restrict__ bucketPtr,
                                                  const int* __restrict__ blockBase,
                                                  int2* __restrict__ ebuf) {
    __shared__ int lh[256];
    lh[threadIdx.x] = 0;
    __syncthreads();
    int base = blockIdx.x * 2048;
    const int* bb = &blockBase[blockIdx.x * 256];
#pragma unroll
    for (int i = 0; i < 8; ++i) {
        int e = base + i * 256 + threadIdx.x;
        if (e < E) {
            int src = ei[e];
            int dst = ei[E + e];
            int b = dst >> 8;
            int lp = atomicAdd(&lh[b], 1);
            ebuf[bucketPtr[b] + bb[b] + lp] = int2{src, dst};
        }
    }
}

// ---- Pass C: per-bucket counting sort -> csr, rowptr, dinv ----
__global__ __launch_bounds__(256) void k_bcsr(const int2* __restrict__ ebuf,
                                              const int* __restrict__ bucketPtr,
                                              int* __restrict__ rowptr, float* __restrict__ dinv,
                                              int* __restrict__ csr, int N) {
    __shared__ int hist[256], excl[256], cur[256];
    const int b = blockIdx.x;
    const int base = bucketPtr[b];
    const int cnt = bucketPtr[b + 1] - base;
    const int t = threadIdx.x;
    hist[t] = 0;
    cur[t] = 0;
    __syncthreads();
    for (int i = t; i < cnt; i += 256) atomicAdd(&hist[ebuf[base + i].y & 255], 1);
    __syncthreads();
    int v = hist[t];
    excl[t] = v;
    __syncthreads();
    for (int off = 1; off < 256; off <<= 1) {
        int x = (t >= off) ? excl[t - off] : 0;
        __syncthreads();
        excl[t] += x;
        __syncthreads();
    }
    int ex = excl[t] - v;
    int node = b * 256 + t;
    if (node < N) {
        rowptr[node] = base + ex;
        dinv[node] = rsqrtf((float)(v + 1));  // +1 self-loop
    }
    __syncthreads();
    excl[t] = ex;
    __syncthreads();
    for (int i = t; i < cnt; i += 256) {
        int2 e = ebuf[base + i];
        int ln = e.y & 255;
        int pos = base + excl[ln] + atomicAdd(&cur[ln], 1);
        csr[pos] = e.x;
    }
}

__global__ __launch_bounds__(256) void k_f2h(const float* __restrict__ x, __half* __restrict__ y,
                                             int n4) {
    int i = blockIdx.x * 256 + threadIdx.x;
    if (i >= n4) return;
    float4 v = ((const float4*)x)[i];
    __half h[4] = {__float2half_rn(v.x), __float2half_rn(v.y), __float2half_rn(v.z),
                   __float2half_rn(v.w)};
    ((uint2*)y)[i] = *(uint2*)h;
}

// one fused kernel for all 5 weight transposes: W[K x FO] f32 -> Wt[FOP x K] f16
__device__ inline bool wt_job(int i, int lo, int hi, int K, int FO, const float* W, __half* T) {
    if (i < lo || i >= hi) return false;
    int j = i - lo;
    int c = j / K;
    int k = j - c * K;
    T[j] = (c < FO) ? __float2half_rn(W[(size_t)k * FO + c]) : __half(0.f);
    return true;
}

__global__ __launch_bounds__(256) void k_wt_all(const float* w1, const float* w2, const float* w3,
                                                const float* w4, const float* w5, __half* t1,
                                                __half* t2, __half* t3, __half* t4, __half* t5) {
    int i = blockIdx.x * 256 + threadIdx.x;
    // sizes: 16384, 16384, 32768 (FOP256,K128), 32768 (FOP128,K256), 8192 (FOP64,K128,FO40)
    if (wt_job(i, 0, 16384, 128, 128, w1, t1)) return;
    if (wt_job(i, 16384, 32768, 128, 128, w2, t2)) return;
    if (wt_job(i, 32768, 65536, 128, 256, w3, t3)) return;
    if (wt_job(i, 65536, 98304, 256, 128, w4, t4)) return;
    wt_job(i, 98304, 106496, 128, 40, w5, t5);
}

// CSR gather over 128-wide fp16 rows -> fp16 out (fp32 accum).
// 64 lanes per node (one wave), 4B (__half2) per lane per edge, 8-edge unroll.
__global__ __launch_bounds__(256) void k_gather64(const int* __restrict__ rowptr,
                                                  const int* __restrict__ csr,
                                                  const float* __restrict__ dinv,
                                                  const __half* __restrict__ xh,
                                                  __half* __restrict__ G, int N) {
    int t = blockIdx.x * 256 + threadIdx.x;
    int node = t >> 6;
    if (node >= N) return;
    int lane = t & 63;
    const __half2* xb = (const __half2*)xh;  // 64 half2 per row
    float di = dinv[node];
    float ax, ay;
    {
        float2 f = __half22float2(xb[(size_t)node * 64 + lane]);
        float s = di * di;
        ax = s * f.x;
        ay = s * f.y;
    }
    int p0 = rowptr[node], p1 = rowptr[node + 1];
    int p = p0;
    for (; p + 8 <= p1; p += 8) {
        int s_[8];
        float wg[8];
        __half2 v[8];
#pragma unroll
        for (int j = 0; j < 8; ++j) s_[j] = csr[p + j];
#pragma unroll
        for (int j = 0; j < 8; ++j) wg[j] = di * dinv[s_[j]];
#pragma unroll
        for (int j = 0; j < 8; ++j) v[j] = xb[(size_t)s_[j] * 64 + lane];
#pragma unroll
        for (int j = 0; j < 8; ++j) {
            float2 f = __half22float2(v[j]);
            ax += wg[j] * f.x;
            ay += wg[j] * f.y;
        }
    }
    for (; p + 4 <= p1; p += 4) {
        int s_[4];
        float wg[4];
        __half2 v[4];
#pragma unroll
        for (int j = 0; j < 4; ++j) s_[j] = csr[p + j];
#pragma unroll
        for (int j = 0; j < 4; ++j) wg[j] = di * dinv[s_[j]];
#pragma unroll
        for (int j = 0; j < 4; ++j) v[j] = xb[(size_t)s_[j] * 64 + lane];
#pragma unroll
        for (int j = 0; j < 4; ++j) {
            float2 f = __half22float2(v[j]);
            ax += wg[j] * f.x;
            ay += wg[j] * f.y;
        }
    }
    for (; p < p1; ++p) {
        int src = csr[p];
        float w = di * dinv[src];
        float2 f = __half22float2(xb[(size_t)src * 64 + lane]);
        ax += w * f.x;
        ay += w * f.y;
    }
    ((__half2*)G)[(size_t)node * 64 + lane] = __floats2half2_rn(ax, ay);
}

// ---------------------------------------------------------------------------
// MFMA fp16 GEMM, fused epilogue (BN+ReLU / bias+ReLU / bias).
// Block = 4 waves; tile 128 rows x 64 cols; wave = 32x64.
// C/D: col=lane&15, row=(lane>>4)*4+reg  [HW-verified m89/m91].
// ncols masks bias load + stores (for FO=40 padded to 64).
// ---------------------------------------------------------------------------
template <int K, bool BN, bool RELU, typename OT>
__global__ __launch_bounds__(256) void k_mfma(const __half* __restrict__ A,
                                              const __half* __restrict__ Wt,
                                              const float* __restrict__ cb,
                                              const float* __restrict__ g,
                                              const float* __restrict__ bb,
                                              const float* __restrict__ m,
                                              const float* __restrict__ vv,
                                              OT* __restrict__ Y, int ldy, int N, int ncols) {
    constexpr int KS = K / 32;
    constexpr int NCT = 4;  // 64 cols
    __shared__ __half bs[KS * NCT * 64 * 8];

    const int tid = threadIdx.x;
    const int col0 = blockIdx.y * 64;

    constexpr int PIECES = KS * NCT * 64;
#pragma unroll
    for (int p = tid; p < PIECES; p += 256) {
        int ks = p / (NCT * 64);
        int rem = p - ks * (NCT * 64);
        int ct = rem >> 6;
        int l = rem & 63;
        int col = col0 + ct * 16 + (l & 15);
        int kg = ks * 32 + (l >> 4) * 8;
        *(uint4*)&bs[p * 8] = *(const uint4*)&Wt[(size_t)col * K + kg];
    }
    __syncthreads();

    const int wave = tid >> 6;
    const int lane = tid & 63;
    const int rbase = blockIdx.x * 128 + wave * 32;
    const int r0 = rbase + (lane & 15);
    const int k0 = (lane >> 4) * 8;

    uint4 af[2][KS];
#pragma unroll
    for (int ks = 0; ks < KS; ++ks) {
        int kk = ks * 32 + k0;
        af[0][ks] = (r0 < N) ? *(const uint4*)&A[(size_t)r0 * K + kk] : uint4{0, 0, 0, 0};
        af[1][ks] = (r0 + 16 < N) ? *(const uint4*)&A[(size_t)(r0 + 16) * K + kk]
                                  : uint4{0, 0, 0, 0};
    }

    f32x4 acc[2][NCT];
#pragma unroll
    for (int rt = 0; rt < 2; ++rt)
#pragma unroll
        for (int ct = 0; ct < NCT; ++ct) acc[rt][ct] = {0.f, 0.f, 0.f, 0.f};

#pragma unroll
    for (int ks = 0; ks < KS; ++ks) {
        f16x8 b[NCT];
#pragma unroll
        for (int ct = 0; ct < NCT; ++ct)
            b[ct] = *(const f16x8*)&bs[((ks * NCT + ct) * 64 + lane) * 8];
#pragma unroll
        for (int rt = 0; rt < 2; ++rt) {
            f16x8 a = *(const f16x8*)&af[rt][ks];
#pragma unroll
            for (int ct = 0; ct < NCT; ++ct)
                acc[rt][ct] = __builtin_amdgcn_mfma_f32_16x16x32_f16(a, b[ct], acc[rt][ct], 0, 0, 0);
        }
    }

    const int cbase = col0 + (lane & 15);
#pragma unroll
    for (int ct = 0; ct < NCT; ++ct) {
        int col = cbase + ct * 16;
        if (col >= ncols) continue;
        float sc, sh;
        if (BN) {
            sc = g[col] * rsqrtf(vv[col] + 1e-5f);
            sh = bb[col] + (cb[col] - m[col]) * sc;
        } else {
            sc = 1.f;
            sh = cb[col];
        }
#pragma unroll
        for (int rt = 0; rt < 2; ++rt) {
#pragma unroll
            for (int r = 0; r < 4; ++r) {
                int row = rbase + rt * 16 + (lane >> 4) * 4 + r;
                if (row < N) {
                    float o = acc[rt][ct][r] * sc + sh;
                    if (RELU) o = fmaxf(o, 0.f);
                    if constexpr (sizeof(OT) == 2) {
                        Y[(size_t)row * ldy + col] = __float2half_rn(o);
                    } else {
                        Y[(size_t)row * ldy + col] = o;
                    }
                }
            }
        }
    }
}

extern "C" void kernel_launch(void* const* d_in, const int* in_sizes, int n_in,
                              void* d_out, int out_size, void* d_ws, size_t ws_size,
                              hipStream_t stream) {
    const float* x = (const float*)d_in[0];
    const int* ei = (const int*)d_in[1];
    const float* cw1 = (const float*)d_in[2];
    const float* cb1 = (const float*)d_in[3];
    const float* g1 = (const float*)d_in[4];
    const float* bb1 = (const float*)d_in[5];
    const float* m1 = (const float*)d_in[6];
    const float* v1 = (const float*)d_in[7];
    const float* cw2 = (const float*)d_in[8];
    const float* cb2 = (const float*)d_in[9];
    const float* g2 = (const float*)d_in[10];
    const float* bb2 = (const float*)d_in[11];
    const float* m2 = (const float*)d_in[12];
    const float* v2 = (const float*)d_in[13];
    const float* cw3 = (const float*)d_in[14];
    const float* cb3 = (const float*)d_in[15];
    const float* g3 = (const float*)d_in[16];
    const float* bb3 = (const float*)d_in[17];
    const float* m3 = (const float*)d_in[18];
    const float* v3 = (const float*)d_in[19];
    const float* lw1 = (const float*)d_in[20];
    const float* lb1 = (const float*)d_in[21];
    const float* lw2 = (const float*)d_in[22];
    const float* lb2 = (const float*)d_in[23];
    float* out = (float*)d_out;

    const int N = in_sizes[0] / 128;
    const int E = in_sizes[1] / 2;
    const int NBK = cdiv(N, 256);          // dst buckets of 256 nodes
    const int NBA = cdiv(E, 2048);         // pass A/B blocks

    auto al = [](size_t v) { return (v + 255) & ~(size_t)255; };
    char* w = (char*)d_ws;
    size_t o = 0;
    float* dinv  = (float*)(w + o);  o = al(o + (size_t)N * 4);
    int* rowptr  = (int*)(w + o);    o = al(o + (size_t)(N + 1) * 4);
    int* bcount  = (int*)(w + o);    o = al(o + 256 * 4);
    int* bptr    = (int*)(w + o);    o = al(o + (256 + 1) * 4);
    int* bbase   = (int*)(w + o);    o = al(o + (size_t)NBA * 256 * 4);
    int2* ebuf   = (int2*)(w + o);   o = al(o + (size_t)E * 8);
    int* csr     = (int*)(w + o);    o = al(o + (size_t)E * 4);
    __half* XH   = (__half*)(w + o); o = al(o + (size_t)N * 128 * 2);
    __half* GH   = (__half*)(w + o); o = al(o + (size_t)N * 128 * 2);
    __half* H3h  = (__half*)(w + o); o = al(o + (size_t)N * 256 * 2);
    __half* Wt1  = (__half*)(w + o); o = al(o + (size_t)128 * 128 * 2);
    __half* Wt2  = (__half*)(w + o); o = al(o + (size_t)128 * 128 * 2);
    __half* Wt3  = (__half*)(w + o); o = al(o + (size_t)256 * 128 * 2);
    __half* Wt4  = (__half*)(w + o); o = al(o + (size_t)128 * 256 * 2);
    __half* Wt5  = (__half*)(w + o); o = al(o + (size_t)64 * 128 * 2);
    __half* Zh   = GH;  // lin1 output overlays GH (dead after conv3 GEMM)

    // ---- CSR build (bucketed counting sort) ----
    k_zero_int<<<1, 256, 0, stream>>>(bcount, 256);
    k_bcount<<<NBA, 256, 0, stream>>>(ei, E, bcount, bbase);
    k_bscan<<<1, 1024, 0, stream>>>(bcount, bptr, NBK, rowptr, N, E);
    k_bscatter<<<NBA, 256, 0, stream>>>(ei, E, bptr, bbase, ebuf);
    k_bcsr<<<NBK, 256, 0, stream>>>(ebuf, bptr, rowptr, dinv, csr, N);

    // ---- conversions ----
    k_f2h<<<cdiv(N * 32, 256), 256, 0, stream>>>(x, XH, N * 32);
    k_wt_all<<<cdiv(106496, 256), 256, 0, stream>>>(cw1, cw2, cw3, lw1, lw2, Wt1, Wt2, Wt3, Wt4,
                                                    Wt5);

    const int gx = cdiv(N, 128);

    // ---- conv1
    k_gather64<<<cdiv(N, 4), 256, 0, stream>>>(rowptr, csr, dinv, XH, GH, N);
    k_mfma<128, true, true, __half><<<dim3(gx, 2), 256, 0, stream>>>(
        GH, Wt1, cb1, g1, bb1, m1, v1, XH, 128, N, 128);
    // ---- conv2
    k_gather64<<<cdiv(N, 4), 256, 0, stream>>>(rowptr, csr, dinv, XH, GH, N);
    k_mfma<128, true, true, __half><<<dim3(gx, 2), 256, 0, stream>>>(
        GH, Wt2, cb2, g2, bb2, m2, v2, XH, 128, N, 128);
    // ---- conv3 (FO=256)
    k_gather64<<<cdiv(N, 4), 256, 0, stream>>>(rowptr, csr, dinv, XH, GH, N);
    k_mfma<128, true, true, __half><<<dim3(gx, 4), 256, 0, stream>>>(
        GH, Wt3, cb3, g3, bb3, m3, v3, H3h, 256, N, 256);
    // ---- lin1: Zh = relu(H3h @ lw1 + lb1)
    k_mfma<256, false, true, __half><<<dim3(gx, 2), 256, 0, stream>>>(
        H3h, Wt4, lb1, nullptr, nullptr, nullptr, nullptr, Zh, 128, N, 128);
    // ---- lin2: out = Zh @ lw2 + lb2 (fp32, 40 cols)
    k_mfma<128, false, false, float><<<dim3(gx, 1), 256, 0, stream>>>(
        Zh, Wt5, lb2, nullptr, nullptr, nullptr, nullptr, out, 40, N, 40);
}